// Round 8
// baseline (264.234 us; speedup 1.0000x reference)
//
#include <hip/hip_runtime.h>
#include <cmath>

// R12 = R11 (best total 263.0: direct-MFMA gram, ring-3 prefetch, phase
// skew, R9 tail) with ONE isolated change: NON-TEMPORAL global loads.
// Mechanism (over-constrained by R4-R11): per-CU read BW pinned at
// ~10 GB/s (2.55 TB/s aggregate) across 7 structures; warm==cold; all
// pipes <25%. Only latency x in-flight-cap fits: ~4KB (~32 lines) in
// flight per CU => L1 line-tracking (MSHR) cap. Every wave-instruction
// here touches 8-16 DISTINCT 128B lines, so 1-2 load instructions per CU
// are in flight regardless of ring depth -- exactly what we measured.
// NT loads bypass L1 (global_load_dwordx4 ... nt) and queue in the deeper
// L2/fabric path; data is streamed once so L1 had no caching value anyway.
// Numerics bit-identical. If gram stays ~92us, the cap is below L1 and
// ~92us is this op's machine floor (declared next round).

#define TPB 256
#define WCOLS 256                     // per-wave window: 8 chunks of K=32
#define COLS_PER_BLOCK 1024
#define NSTEP 60

typedef short short8 __attribute__((ext_vector_type(8)));   // 8 x bf16 frag
typedef float f32x4 __attribute__((ext_vector_type(4)));    // MFMA acc / loads

struct EpsList { float e[NSTEP]; };

struct GramArgs {
  const float* x0; const float* y0;
  const float* x1; const float* y1;
  const float* x2; const float* y2;
  int M0, M1, M2;
  int bs1, bs2, bsTot;
  float* partial;       // [block][800] fp32
  double* finalG;       // [3][800] (atomic fallback)
  int atomicMode;
};

__device__ __forceinline__ short f2bf_rne(float f) {
  unsigned u = __float_as_uint(f);
  u += 0x7FFFu + ((u >> 16) & 1u);
  return (short)(u >> 16);
}
__device__ __forceinline__ float bf2f(short h) {
  return __uint_as_float(((unsigned)(unsigned short)h) << 16);
}
// Non-temporal 16B load: bypasses L1 line-tracking (the measured cap).
__device__ __forceinline__ f32x4 ntload(const float* p) {
  return __builtin_nontemporal_load(reinterpret_cast<const f32x4*>(p));
}

#define SPLIT(HI, LO, J, VAL)                                   \
  { const float fv_ = (VAL); const short hh_ = f2bf_rne(fv_);   \
    HI[J] = hh_; LO[J] = f2bf_rne(fv_ - bf2f(hh_)); }

__global__ __launch_bounds__(TPB) void gram_kernel(GramArgs A) {
  __shared__ __align__(16) float sB[4][800];

  const int bid = blockIdx.x;
  int p, lb;
  if (bid >= A.bs2)      { p = 2; lb = bid - A.bs2; }
  else if (bid >= A.bs1) { p = 1; lb = bid - A.bs1; }
  else                   { p = 0; lb = bid; }
  const float* X = (p == 0) ? A.x0 : (p == 1) ? A.x1 : A.x2;
  const float* Y = (p == 0) ? A.y0 : (p == 1) ? A.y1 : A.y2;
  const int M    = (p == 0) ? A.M0 : (p == 1) ? A.M1 : A.M2;

  const int t    = threadIdx.x;
  const int w    = t >> 6;
  const int lane = t & 63;
  const int r    = lane & 15;    // fragment row
  const int kg   = lane >> 4;    // k-group (8 contiguous k)

  const size_t wbase = (size_t)(4 * lb + w) * WCOLS;
  const float* bx = X + (size_t)r * M + wbase + 8 * kg;
  const float* by = Y + (size_t)r * M + wbase + 8 * kg;
  const int phase = (lb + 3 * w) & 7;   // de-phased chunk order

  f32x4 aXY = {0.f, 0.f, 0.f, 0.f};
  f32x4 aXX = {0.f, 0.f, 0.f, 0.f};
  f32x4 aYY = {0.f, 0.f, 0.f, 0.f};
  f32x4 aZX = {0.f, 0.f, 0.f, 0.f};
  f32x4 aZY = {0.f, 0.f, 0.f, 0.f};
  short8 ones;
  #pragma unroll
  for (int j = 0; j < 8; ++j) ones[j] = (short)0x3F80;   // bf16 1.0

  // 4-slot register ring; fully unrolled -> static slot indices (rule #20).
  f32x4 RX0[4], RX1[4], RY0[4], RY1[4];
  #pragma unroll
  for (int q = 0; q < 3; ++q) {         // prologue: chunks 0,1,2 in flight
    const int cq = (phase + q) & 7;
    RX0[q] = ntload(bx + cq * 32);
    RX1[q] = ntload(bx + cq * 32 + 4);
    RY0[q] = ntload(by + cq * 32);
    RY1[q] = ntload(by + cq * 32 + 4);
  }

  #pragma unroll
  for (int c = 0; c < 8; ++c) {
    const int slot = c & 3;
    if (c + 3 < 8) {                    // issue BEFORE compute: 3 phases ahead
      const int cn = (phase + c + 3) & 7;
      const int ns = (c + 3) & 3;
      RX0[ns] = ntload(bx + cn * 32);
      RX1[ns] = ntload(bx + cn * 32 + 4);
      RY0[ns] = ntload(by + cn * 32);
      RY1[ns] = ntload(by + cn * 32 + 4);
    }
    const f32x4 xc0 = RX0[slot], xc1 = RX1[slot];
    const f32x4 yc0 = RY0[slot], yc1 = RY1[slot];

    short8 hx, lx, hy, ly;
    SPLIT(hx, lx, 0, __expf(xc0.x)); SPLIT(hx, lx, 1, __expf(xc0.y));
    SPLIT(hx, lx, 2, __expf(xc0.z)); SPLIT(hx, lx, 3, __expf(xc0.w));
    SPLIT(hx, lx, 4, __expf(xc1.x)); SPLIT(hx, lx, 5, __expf(xc1.y));
    SPLIT(hx, lx, 6, __expf(xc1.z)); SPLIT(hx, lx, 7, __expf(xc1.w));
    SPLIT(hy, ly, 0, __expf(yc0.x)); SPLIT(hy, ly, 1, __expf(yc0.y));
    SPLIT(hy, ly, 2, __expf(yc0.z)); SPLIT(hy, ly, 3, __expf(yc0.w));
    SPLIT(hy, ly, 4, __expf(yc1.x)); SPLIT(hy, ly, 5, __expf(yc1.y));
    SPLIT(hy, ly, 6, __expf(yc1.z)); SPLIT(hy, ly, 7, __expf(yc1.w));

    // round-robin over 5 accumulators -> dep distance >= 5
    aXY = __builtin_amdgcn_mfma_f32_16x16x32_bf16(hx, hy, aXY, 0, 0, 0);
    aXX = __builtin_amdgcn_mfma_f32_16x16x32_bf16(hx, hx, aXX, 0, 0, 0);
    aYY = __builtin_amdgcn_mfma_f32_16x16x32_bf16(hy, hy, aYY, 0, 0, 0);
    aZX = __builtin_amdgcn_mfma_f32_16x16x32_bf16(hx, ones, aZX, 0, 0, 0);
    aZY = __builtin_amdgcn_mfma_f32_16x16x32_bf16(hy, ones, aZY, 0, 0, 0);
    aXY = __builtin_amdgcn_mfma_f32_16x16x32_bf16(hx, ly, aXY, 0, 0, 0);
    aXX = __builtin_amdgcn_mfma_f32_16x16x32_bf16(hx, lx, aXX, 0, 0, 0);
    aYY = __builtin_amdgcn_mfma_f32_16x16x32_bf16(hy, ly, aYY, 0, 0, 0);
    aZX = __builtin_amdgcn_mfma_f32_16x16x32_bf16(lx, ones, aZX, 0, 0, 0);
    aZY = __builtin_amdgcn_mfma_f32_16x16x32_bf16(ly, ones, aZY, 0, 0, 0);
    aXY = __builtin_amdgcn_mfma_f32_16x16x32_bf16(lx, hy, aXY, 0, 0, 0);
    aXX = __builtin_amdgcn_mfma_f32_16x16x32_bf16(lx, hx, aXX, 0, 0, 0);
    aYY = __builtin_amdgcn_mfma_f32_16x16x32_bf16(ly, hy, aYY, 0, 0, 0);
  }

  // C layout (HW-verified, R8-R11 passed): col = lane&15, row = kg*4 + j.
  if (A.atomicMode) {
    double* fin = A.finalG + (size_t)p * 800;
    #pragma unroll
    for (int j = 0; j < 4; ++j) {
      const int ib = (4 * kg + j) * 16 + r;
      atomicAdd(&fin[ib],       (double)aXY[j]);
      atomicAdd(&fin[256 + ib], (double)aXX[j]);
      atomicAdd(&fin[512 + ib], (double)aYY[j]);
    }
    if (r == 0) {
      #pragma unroll
      for (int j = 0; j < 4; ++j) {
        atomicAdd(&fin[768 + 4 * kg + j], (double)aZX[j]);
        atomicAdd(&fin[784 + 4 * kg + j], (double)aZY[j]);
      }
    }
    return;
  }

  float* b = sB[w];
  #pragma unroll
  for (int j = 0; j < 4; ++j) {
    const int ib = (4 * kg + j) * 16 + r;
    b[ib]       = aXY[j];
    b[256 + ib] = aXX[j];
    b[512 + ib] = aYY[j];
  }
  if (r == 0) {
    #pragma unroll
    for (int j = 0; j < 4; ++j) {
      b[768 + 4 * kg + j] = aZX[j];
      b[784 + 4 * kg + j] = aZY[j];
    }
  }
  __syncthreads();
  if (t < 200) {
    const int o4 = 4 * t;
    const float4 v0 = *reinterpret_cast<const float4*>(&sB[0][o4]);
    const float4 v1 = *reinterpret_cast<const float4*>(&sB[1][o4]);
    const float4 v2 = *reinterpret_cast<const float4*>(&sB[2][o4]);
    const float4 v3 = *reinterpret_cast<const float4*>(&sB[3][o4]);
    const float4 o = make_float4((v0.x + v1.x) + (v2.x + v3.x),
                                 (v0.y + v1.y) + (v2.y + v3.y),
                                 (v0.z + v1.z) + (v2.z + v3.z),
                                 (v0.w + v1.w) + (v2.w + v3.w));
    *reinterpret_cast<float4*>(A.partial + (size_t)bid * 800 + o4) = o;
  }
}

// 16 partial-rows per block, coalesced contiguous reads (3200 B rows),
// fp64 register accumulation, one atomicAdd per value. (R9-proven, ~3us.)
__global__ __launch_bounds__(256) void reduce_kernel(const float* __restrict__ partial,
                                                     double* __restrict__ finalG,
                                                     int nb0, int nb1, int nb2) {
  const int c0 = (nb0 + 15) >> 4, c1 = (nb1 + 15) >> 4;
  const int b = blockIdx.x;
  int p, r0, pstart, cnt;
  if (b < c0)           { p = 0; r0 = b << 4;             pstart = 0;         cnt = nb0; }
  else if (b < c0 + c1) { p = 1; r0 = (b - c0) << 4;      pstart = nb0;       cnt = nb1; }
  else                  { p = 2; r0 = (b - c0 - c1) << 4; pstart = nb0 + nb1; cnt = nb2; }
  const int rows = min(16, cnt - r0);
  const float* src = partial + (size_t)(pstart + r0) * 800;
  const int tt = threadIdx.x;
  double s0 = 0.0, s1 = 0.0, s2 = 0.0, s3 = 0.0;
  #pragma unroll 1
  for (int rr = 0; rr < rows; ++rr) {
    const float* row = src + (size_t)rr * 800;
    s0 += (double)row[tt];
    s1 += (double)row[tt + 256];
    s2 += (double)row[tt + 512];
    if (tt < 32) s3 += (double)row[768 + tt];
  }
  double* fin = finalG + (size_t)p * 800;
  atomicAdd(&fin[tt], s0);
  atomicAdd(&fin[tt + 256], s1);
  atomicAdd(&fin[tt + 512], s2);
  if (tt < 32) atomicAdd(&fin[768 + tt], s3);
}

__device__ __forceinline__ float expm1_poly(float d) {
  float pp = 1.0f / 120.0f;
  pp = fmaf(pp, d, 1.0f / 24.0f);
  pp = fmaf(pp, d, 1.0f / 6.0f);
  pp = fmaf(pp, d, 0.5f);
  return fmaf(d * d, pp, d);
}
__device__ __forceinline__ float log1p_poly(float w) {
  float pp = -1.0f / 6.0f;
  pp = fmaf(pp, w, 1.0f / 5.0f);
  pp = fmaf(pp, w, -1.0f / 4.0f);
  pp = fmaf(pp, w, 1.0f / 3.0f);
  pp = fmaf(pp, w, -0.5f);
  return fmaf(w * w, pp, w);
}

__device__ float run_chain(const double* __restrict__ G, int half, int lane,
                           const EpsList& E) {
  const int pot = lane >> 5;
  const int i   = (lane >> 1) & 15;
  const int jh  = lane & 1;

  float Crow[8];
  #pragma unroll
  for (int jj = 0; jj < 8; ++jj) {
    const int j = jh * 8 + jj;
    double Cv;
    if (half == 0) {
      const int rr = (pot == 0) ? i : j;
      const int cc = (pot == 0) ? j : i;
      const double zr = G[768 + rr], zc = G[784 + cc];
      const double sr = G[256 + 17 * rr] / (zr * zr);
      const double sc = G[512 + 17 * cc] / (zc * zc);
      Cv = 0.5 * (sr + sc) - G[16 * rr + cc] / (zr * zc);
    } else if (pot == 0) {
      const double zi_ = G[768 + i], zj_ = G[768 + j];
      const double si_ = G[256 + 17 * i] / (zi_ * zi_);
      const double sj_ = G[256 + 17 * j] / (zj_ * zj_);
      Cv = 0.5 * (si_ + sj_) - G[256 + 16 * i + j] / (zi_ * zj_);
    } else {
      const double zi_ = G[784 + i], zj_ = G[784 + j];
      const double si_ = G[512 + 17 * i] / (zi_ * zi_);
      const double sj_ = G[512 + 17 * j] / (zj_ * zj_);
      Cv = 0.5 * (si_ + sj_) - G[512 + 16 * i + j] / (zi_ * zj_);
    }
    Crow[jj] = (float)Cv;
  }

  const int srcBase = (half == 0) ? ((pot == 0) ? 32 : 0)
                                  : ((pot == 0) ? 0 : 32);
  float h = 0.0f;
  #pragma unroll 1
  for (int n = 0; n < NSTEP; ++n) {
    const float eps  = E.e[n];
    const float inve = 1.0f / eps;
    float q = 0.0f;
    #pragma unroll
    for (int jj = 0; jj < 8; ++jj) {
      const float hj = __shfl(h, srcBase + 2 * (jh * 8 + jj));
      q += expm1_poly((hj - Crow[jj]) * inve);
    }
    q += __shfl_xor(q, 1);
    const float val = -eps * log1p_poly(q * (1.0f / 16.0f));
    h = 0.5f * (h + val);
  }
  {
    const float eps  = 0.0025f;
    const float inve = 1.0f / eps;
    float q = 0.0f;
    #pragma unroll
    for (int jj = 0; jj < 8; ++jj) {
      const float hj = __shfl(h, srcBase + 2 * (jh * 8 + jj));
      q += expm1_poly((hj - Crow[jj]) * inve);
    }
    q += __shfl_xor(q, 1);
    h = -eps * log1p_poly(q * (1.0f / 16.0f));
  }
  return h;
}

// 6 waves in ONE block; finalize fused after __syncthreads.
__global__ __launch_bounds__(384) void sinkhorn_kernel(const double* __restrict__ finalG,
                                                       float* __restrict__ out, EpsList E) {
  __shared__ double res[6];
  const int tt   = threadIdx.x;
  const int grp  = tt >> 6;
  const int p    = grp >> 1;
  const int half = grp & 1;
  const int lane = tt & 63;
  float h = run_chain(finalG + p * 800, half, lane, E);
  float sAcc = h;
  #pragma unroll
  for (int d = 1; d <= 32; d <<= 1) sAcc += __shfl_xor(sAcc, d);
  if (lane == 0) res[grp] = (double)(sAcc * (1.0f / 32.0f));
  __syncthreads();
  if (tt == 0) {
    const double v = (res[0] - res[1]) + (res[2] - res[3]) + (res[4] - res[5]);
    out[0] = (float)(v / 3.0);
  }
}

extern "C" void kernel_launch(void* const* d_in, const int* in_sizes, int n_in,
                              void* d_out, int out_size, void* d_ws, size_t ws_size,
                              hipStream_t stream) {
  (void)n_in; (void)out_size;
  int idx[6] = {0, 1, 2, 3, 4, 5};
  for (int a = 1; a < 6; ++a) {
    const int key = idx[a];
    int b = a - 1;
    while (b >= 0 && in_sizes[idx[b]] < in_sizes[key]) { idx[b + 1] = idx[b]; --b; }
    idx[b + 1] = key;
  }

  const float* xs[3]; const float* ys[3]; int Ms[3]; int nb[3];
  for (int p = 0; p < 3; ++p) {
    xs[p] = (const float*)d_in[idx[2 * p]];
    ys[p] = (const float*)d_in[idx[2 * p + 1]];
    Ms[p] = in_sizes[idx[2 * p]] / 16;
    nb[p] = Ms[p] / COLS_PER_BLOCK;
  }
  const int totalBlocks = nb[0] + nb[1] + nb[2];
  const int rb = ((nb[0] + 15) / 16) + ((nb[1] + 15) / 16) + ((nb[2] + 15) / 16);

  const size_t partialBytes = (size_t)totalBlocks * 800 * sizeof(float);
  const size_t finalBytes   = (size_t)2400 * sizeof(double);
  const bool partialMode    = (ws_size >= partialBytes + finalBytes);

  char* wsb      = (char*)d_ws;
  float* partial = partialMode ? (float*)wsb : nullptr;
  double* finalG = (double*)(wsb + (partialMode ? partialBytes : 0));

  hipMemsetAsync(finalG, 0, finalBytes, stream);

  EpsList E;
  const double base = 0.95 * 0.95;
  for (int n = 0; n < NSTEP; ++n) {
    double v = pow(base, (double)n);
    if (v < 0.0025) v = 0.0025;
    E.e[n] = (float)v;
  }

  GramArgs A;
  A.x0 = xs[0]; A.y0 = ys[0];
  A.x1 = xs[1]; A.y1 = ys[1];
  A.x2 = xs[2]; A.y2 = ys[2];
  A.M0 = Ms[0]; A.M1 = Ms[1]; A.M2 = Ms[2];
  A.bs1 = nb[0]; A.bs2 = nb[0] + nb[1]; A.bsTot = totalBlocks;
  A.partial = partial; A.finalG = finalG;
  A.atomicMode = partialMode ? 0 : 1;

  gram_kernel<<<dim3(totalBlocks), dim3(TPB), 0, stream>>>(A);
  if (partialMode)
    reduce_kernel<<<dim3(rb), dim3(256), 0, stream>>>(partial, finalG, nb[0], nb[1], nb[2]);
  sinkhorn_kernel<<<dim3(1), dim3(384), 0, stream>>>(finalG, (float*)d_out, E);
}

// Round 9
// 236.777 us; speedup vs baseline: 1.1160x; 1.1160x over previous
//
#include <hip/hip_runtime.h>
#include <cmath>

// R13 = R12 (NT loads, direct-MFMA, barrier-free; gram 75us, BW 1.78TB/s)
// with ONE structural change: load SHAPE. R12's loads touch 16 distinct
// 4KB pages per instruction (16 rows x 4MB stride); per-CU live-page set
// ~224 >> UTCL1; delivered BW matches ONE wave's latency-bound throughput
// (2.9 B/cyc/CU) => serialized per-instruction address translation is the
// post-NT limiter hypothesis. R13 loads CONTIGUOUSLY: per instruction,
// 64 lanes = 4 rows x 256B (4 pages/instr, 4x fewer translations), then
// redistributes to MFMA fragment layout through wave-private 8KB LDS
// (exp + bf16 hi/lo split at stage, XOR swizzle ^(row&7)<<4, same-wave
// DS ordering -> NO barriers in main loop; pattern verified R5-R7).
// 64-col super-chunks, register ring depth 2 (64 VGPR - small enough the
// compiler keeps it; R12's ring-3 was provably sunk: VGPR_Count=44 < ring).
// Numerics identical to R8-R12 (same exp/split/13-MFMA k-tiles, ascending
// column order). Tail = R11's proven reduce+sinkhorn split.
// Pre-commit: translation-serialization theory -> gram 45-58us, BW 2.4-3.2;
// UTCL1-capacity theory -> flat 70-80 (then XCD page-grouping or floor).

#define TPB 256
#define WCOLS 256                     // per-wave window
#define SCC 64                        // cols per super-chunk
#define NSC 4                         // super-chunks per wave
#define COLS_PER_BLOCK 1024
#define NSTEP 60

typedef short short8 __attribute__((ext_vector_type(8)));   // 8 x bf16 frag
typedef float f32x4 __attribute__((ext_vector_type(4)));

struct EpsList { float e[NSTEP]; };

struct GramArgs {
  const float* x0; const float* y0;
  const float* x1; const float* y1;
  const float* x2; const float* y2;
  int M0, M1, M2;
  int bs1, bs2, bsTot;
  float* partial;       // [block][800] fp32
  double* finalG;       // [3][800] (atomic fallback)
  int atomicMode;
};

__device__ __forceinline__ short f2bf_rne(float f) {
  unsigned u = __float_as_uint(f);
  u += 0x7FFFu + ((u >> 16) & 1u);
  return (short)(u >> 16);
}
__device__ __forceinline__ float bf2f(short h) {
  return __uint_as_float(((unsigned)(unsigned short)h) << 16);
}
__device__ __forceinline__ f32x4 ntload(const float* p) {
  return __builtin_nontemporal_load(reinterpret_cast<const f32x4*>(p));
}

__global__ __launch_bounds__(TPB) void gram_kernel(GramArgs A) {
  // Per-wave private panel: [mat][plane][16 rows][64 cols] bf16 = 8KB.
  // byte = mat*4096 + plane*2048 + row*128 + (2*col ^ ((row&7)<<4)).
  __shared__ __align__(16) char lds[4][8192];

  const int bid = blockIdx.x;
  int p, lb;
  if (bid >= A.bs2)      { p = 2; lb = bid - A.bs2; }
  else if (bid >= A.bs1) { p = 1; lb = bid - A.bs1; }
  else                   { p = 0; lb = bid; }
  const float* X = (p == 0) ? A.x0 : (p == 1) ? A.x1 : A.x2;
  const float* Y = (p == 0) ? A.y0 : (p == 1) ? A.y1 : A.y2;
  const int M    = (p == 0) ? A.M0 : (p == 1) ? A.M1 : A.M2;

  const int t    = threadIdx.x;
  const int w    = t >> 6;
  const int lane = t & 63;
  char* ldsw = lds[w];

  // loader mapping: rr = row-in-quad, ss = 16B segment (contiguous lanes
  // -> contiguous 256B per row; one instruction = 4 rows x 256B = 4 pages).
  const int rr = lane >> 4;
  const int ss = lane & 15;
  // MFMA fragment mapping (verified R8-R12): r = lane&15, kg = lane>>4.
  const int r  = lane & 15;
  const int kg = lane >> 4;

  const size_t wbase = (size_t)(4 * lb + w) * WCOLS;
  const float* px = X + (size_t)rr * M + wbase + 4 * ss;
  const float* py = Y + (size_t)rr * M + wbase + 4 * ss;

  f32x4 aXY = {0.f, 0.f, 0.f, 0.f};
  f32x4 aXX = {0.f, 0.f, 0.f, 0.f};
  f32x4 aYY = {0.f, 0.f, 0.f, 0.f};
  f32x4 aZX = {0.f, 0.f, 0.f, 0.f};
  f32x4 aZY = {0.f, 0.f, 0.f, 0.f};
  short8 ones;
  #pragma unroll
  for (int j = 0; j < 8; ++j) ones[j] = (short)0x3F80;   // bf16 1.0

  // ring depth 2: 16 f32x4 = 64 VGPR of in-flight data.
  f32x4 VX[2][4], VY[2][4];

  auto issue = [&](int slot, int sc) {
    const size_t off = (size_t)sc * SCC;
    #pragma unroll
    for (int q = 0; q < 4; ++q) {
      VX[slot][q] = ntload(px + (size_t)(4 * q) * M + off);
      VY[slot][q] = ntload(py + (size_t)(4 * q) * M + off);
    }
  };
  auto stage = [&](int slot) {
    #pragma unroll
    for (int m = 0; m < 2; ++m) {
      #pragma unroll
      for (int q = 0; q < 4; ++q) {
        const f32x4 v = m ? VY[slot][q] : VX[slot][q];
        const float e0 = __expf(v.x), e1 = __expf(v.y);
        const float e2 = __expf(v.z), e3 = __expf(v.w);
        const short h0 = f2bf_rne(e0), h1 = f2bf_rne(e1);
        const short h2 = f2bf_rne(e2), h3 = f2bf_rne(e3);
        const short g0 = f2bf_rne(e0 - bf2f(h0)), g1 = f2bf_rne(e1 - bf2f(h1));
        const short g2 = f2bf_rne(e2 - bf2f(h2)), g3 = f2bf_rne(e3 - bf2f(h3));
        const int row = 4 * q + rr;
        const int off = row * 128 + ((ss * 8) ^ ((row & 7) << 4));
        *reinterpret_cast<short4*>(ldsw + m * 4096 +        off) =
            make_short4(h0, h1, h2, h3);
        *reinterpret_cast<short4*>(ldsw + m * 4096 + 2048 + off) =
            make_short4(g0, g1, g2, g3);
      }
    }
  };
  auto ktile = [&](int tt) {
    const int off = r * 128 + ((64 * tt + 16 * kg) ^ ((r & 7) << 4));
    const short8 hx = *reinterpret_cast<const short8*>(ldsw +        off);
    const short8 lx = *reinterpret_cast<const short8*>(ldsw + 2048 + off);
    const short8 hy = *reinterpret_cast<const short8*>(ldsw + 4096 + off);
    const short8 ly = *reinterpret_cast<const short8*>(ldsw + 6144 + off);
    // round-robin over 5 accumulators -> dep distance >= 5
    aXY = __builtin_amdgcn_mfma_f32_16x16x32_bf16(hx, hy, aXY, 0, 0, 0);
    aXX = __builtin_amdgcn_mfma_f32_16x16x32_bf16(hx, hx, aXX, 0, 0, 0);
    aYY = __builtin_amdgcn_mfma_f32_16x16x32_bf16(hy, hy, aYY, 0, 0, 0);
    aZX = __builtin_amdgcn_mfma_f32_16x16x32_bf16(hx, ones, aZX, 0, 0, 0);
    aZY = __builtin_amdgcn_mfma_f32_16x16x32_bf16(hy, ones, aZY, 0, 0, 0);
    aXY = __builtin_amdgcn_mfma_f32_16x16x32_bf16(hx, ly, aXY, 0, 0, 0);
    aXX = __builtin_amdgcn_mfma_f32_16x16x32_bf16(hx, lx, aXX, 0, 0, 0);
    aYY = __builtin_amdgcn_mfma_f32_16x16x32_bf16(hy, ly, aYY, 0, 0, 0);
    aZX = __builtin_amdgcn_mfma_f32_16x16x32_bf16(lx, ones, aZX, 0, 0, 0);
    aZY = __builtin_amdgcn_mfma_f32_16x16x32_bf16(ly, ones, aZY, 0, 0, 0);
    aXY = __builtin_amdgcn_mfma_f32_16x16x32_bf16(lx, hy, aXY, 0, 0, 0);
    aXX = __builtin_amdgcn_mfma_f32_16x16x32_bf16(lx, hx, aXX, 0, 0, 0);
    aYY = __builtin_amdgcn_mfma_f32_16x16x32_bf16(ly, hy, aYY, 0, 0, 0);
  };

  // prologue: SC0, SC1 in flight.
  issue(0, 0);
  issue(1, 1);
  // fully unrolled -> all ring indices static (rule #20).
  #pragma unroll
  for (int s = 0; s < NSC; ++s) {
    const int slot = s & 1;
    stage(slot);                      // waits SC s (vmcnt leaves s+1 in flight)
    if (s + 2 < NSC) issue(slot, s + 2);
    ktile(0);                         // same-wave DS order: reads after writes
    ktile(1);
  }

  // C layout (HW-verified, R8-R12 passed): col = lane&15, row = kg*4 + j.
  if (A.atomicMode) {
    double* fin = A.finalG + (size_t)p * 800;
    #pragma unroll
    for (int j = 0; j < 4; ++j) {
      const int ib = (4 * kg + j) * 16 + r;
      atomicAdd(&fin[ib],       (double)aXY[j]);
      atomicAdd(&fin[256 + ib], (double)aXX[j]);
      atomicAdd(&fin[512 + ib], (double)aYY[j]);
    }
    if (r == 0) {
      #pragma unroll
      for (int j = 0; j < 4; ++j) {
        atomicAdd(&fin[768 + 4 * kg + j], (double)aZX[j]);
        atomicAdd(&fin[784 + 4 * kg + j], (double)aZY[j]);
      }
    }
    return;
  }

  // epilogue: reuse each wave's panel as its 800-float scratch.
  float* b = reinterpret_cast<float*>(ldsw);
  #pragma unroll
  for (int j = 0; j < 4; ++j) {
    const int ib = (4 * kg + j) * 16 + r;
    b[ib]       = aXY[j];
    b[256 + ib] = aXX[j];
    b[512 + ib] = aYY[j];
  }
  if (r == 0) {
    #pragma unroll
    for (int j = 0; j < 4; ++j) {
      b[768 + 4 * kg + j] = aZX[j];
      b[784 + 4 * kg + j] = aZY[j];
    }
  }
  __syncthreads();   // only barrier in the kernel
  if (t < 200) {
    const int o4 = 4 * t;
    const float4 v0 = *reinterpret_cast<const float4*>(lds[0] + 4 * o4);
    const float4 v1 = *reinterpret_cast<const float4*>(lds[1] + 4 * o4);
    const float4 v2 = *reinterpret_cast<const float4*>(lds[2] + 4 * o4);
    const float4 v3 = *reinterpret_cast<const float4*>(lds[3] + 4 * o4);
    const float4 o = make_float4((v0.x + v1.x) + (v2.x + v3.x),
                                 (v0.y + v1.y) + (v2.y + v3.y),
                                 (v0.z + v1.z) + (v2.z + v3.z),
                                 (v0.w + v1.w) + (v2.w + v3.w));
    *reinterpret_cast<float4*>(A.partial + (size_t)bid * 800 + o4) = o;
  }
}

// 16 partial-rows per block, coalesced contiguous reads (3200 B rows),
// fp64 register accumulation, one atomicAdd per value. (R9-proven, ~3us.)
__global__ __launch_bounds__(256) void reduce_kernel(const float* __restrict__ partial,
                                                     double* __restrict__ finalG,
                                                     int nb0, int nb1, int nb2) {
  const int c0 = (nb0 + 15) >> 4, c1 = (nb1 + 15) >> 4;
  const int b = blockIdx.x;
  int p, r0, pstart, cnt;
  if (b < c0)           { p = 0; r0 = b << 4;             pstart = 0;         cnt = nb0; }
  else if (b < c0 + c1) { p = 1; r0 = (b - c0) << 4;      pstart = nb0;       cnt = nb1; }
  else                  { p = 2; r0 = (b - c0 - c1) << 4; pstart = nb0 + nb1; cnt = nb2; }
  const int rows = min(16, cnt - r0);
  const float* src = partial + (size_t)(pstart + r0) * 800;
  const int tt = threadIdx.x;
  double s0 = 0.0, s1 = 0.0, s2 = 0.0, s3 = 0.0;
  #pragma unroll 1
  for (int rw = 0; rw < rows; ++rw) {
    const float* row = src + (size_t)rw * 800;
    s0 += (double)row[tt];
    s1 += (double)row[tt + 256];
    s2 += (double)row[tt + 512];
    if (tt < 32) s3 += (double)row[768 + tt];
  }
  double* fin = finalG + (size_t)p * 800;
  atomicAdd(&fin[tt], s0);
  atomicAdd(&fin[tt + 256], s1);
  atomicAdd(&fin[tt + 512], s2);
  if (tt < 32) atomicAdd(&fin[768 + tt], s3);
}

__device__ __forceinline__ float expm1_poly(float d) {
  float pp = 1.0f / 120.0f;
  pp = fmaf(pp, d, 1.0f / 24.0f);
  pp = fmaf(pp, d, 1.0f / 6.0f);
  pp = fmaf(pp, d, 0.5f);
  return fmaf(d * d, pp, d);
}
__device__ __forceinline__ float log1p_poly(float w) {
  float pp = -1.0f / 6.0f;
  pp = fmaf(pp, w, 1.0f / 5.0f);
  pp = fmaf(pp, w, -1.0f / 4.0f);
  pp = fmaf(pp, w, 1.0f / 3.0f);
  pp = fmaf(pp, w, -0.5f);
  return fmaf(w * w, pp, w);
}

__device__ float run_chain(const double* __restrict__ G, int half, int lane,
                           const EpsList& E) {
  const int pot = lane >> 5;
  const int i   = (lane >> 1) & 15;
  const int jh  = lane & 1;

  float Crow[8];
  #pragma unroll
  for (int jj = 0; jj < 8; ++jj) {
    const int j = jh * 8 + jj;
    double Cv;
    if (half == 0) {
      const int rr = (pot == 0) ? i : j;
      const int cc = (pot == 0) ? j : i;
      const double zr = G[768 + rr], zc = G[784 + cc];
      const double sr = G[256 + 17 * rr] / (zr * zr);
      const double sc = G[512 + 17 * cc] / (zc * zc);
      Cv = 0.5 * (sr + sc) - G[16 * rr + cc] / (zr * zc);
    } else if (pot == 0) {
      const double zi_ = G[768 + i], zj_ = G[768 + j];
      const double si_ = G[256 + 17 * i] / (zi_ * zi_);
      const double sj_ = G[256 + 17 * j] / (zj_ * zj_);
      Cv = 0.5 * (si_ + sj_) - G[256 + 16 * i + j] / (zi_ * zj_);
    } else {
      const double zi_ = G[784 + i], zj_ = G[784 + j];
      const double si_ = G[512 + 17 * i] / (zi_ * zi_);
      const double sj_ = G[512 + 17 * j] / (zj_ * zj_);
      Cv = 0.5 * (si_ + sj_) - G[512 + 16 * i + j] / (zi_ * zj_);
    }
    Crow[jj] = (float)Cv;
  }

  const int srcBase = (half == 0) ? ((pot == 0) ? 32 : 0)
                                  : ((pot == 0) ? 0 : 32);
  float h = 0.0f;
  #pragma unroll 1
  for (int n = 0; n < NSTEP; ++n) {
    const float eps  = E.e[n];
    const float inve = 1.0f / eps;
    float q = 0.0f;
    #pragma unroll
    for (int jj = 0; jj < 8; ++jj) {
      const float hj = __shfl(h, srcBase + 2 * (jh * 8 + jj));
      q += expm1_poly((hj - Crow[jj]) * inve);
    }
    q += __shfl_xor(q, 1);
    const float val = -eps * log1p_poly(q * (1.0f / 16.0f));
    h = 0.5f * (h + val);
  }
  {
    const float eps  = 0.0025f;
    const float inve = 1.0f / eps;
    float q = 0.0f;
    #pragma unroll
    for (int jj = 0; jj < 8; ++jj) {
      const float hj = __shfl(h, srcBase + 2 * (jh * 8 + jj));
      q += expm1_poly((hj - Crow[jj]) * inve);
    }
    q += __shfl_xor(q, 1);
    h = -eps * log1p_poly(q * (1.0f / 16.0f));
  }
  return h;
}

// 6 waves in ONE block; finalize fused after __syncthreads.
__global__ __launch_bounds__(384) void sinkhorn_kernel(const double* __restrict__ finalG,
                                                       float* __restrict__ out, EpsList E) {
  __shared__ double res[6];
  const int tt   = threadIdx.x;
  const int grp  = tt >> 6;
  const int p    = grp >> 1;
  const int half = grp & 1;
  const int lane = tt & 63;
  float h = run_chain(finalG + p * 800, half, lane, E);
  float sAcc = h;
  #pragma unroll
  for (int d = 1; d <= 32; d <<= 1) sAcc += __shfl_xor(sAcc, d);
  if (lane == 0) res[grp] = (double)(sAcc * (1.0f / 32.0f));
  __syncthreads();
  if (tt == 0) {
    const double v = (res[0] - res[1]) + (res[2] - res[3]) + (res[4] - res[5]);
    out[0] = (float)(v / 3.0);
  }
}

extern "C" void kernel_launch(void* const* d_in, const int* in_sizes, int n_in,
                              void* d_out, int out_size, void* d_ws, size_t ws_size,
                              hipStream_t stream) {
  (void)n_in; (void)out_size;
  int idx[6] = {0, 1, 2, 3, 4, 5};
  for (int a = 1; a < 6; ++a) {
    const int key = idx[a];
    int b = a - 1;
    while (b >= 0 && in_sizes[idx[b]] < in_sizes[key]) { idx[b + 1] = idx[b]; --b; }
    idx[b + 1] = key;
  }

  const float* xs[3]; const float* ys[3]; int Ms[3]; int nb[3];
  for (int p = 0; p < 3; ++p) {
    xs[p] = (const float*)d_in[idx[2 * p]];
    ys[p] = (const float*)d_in[idx[2 * p + 1]];
    Ms[p] = in_sizes[idx[2 * p]] / 16;
    nb[p] = Ms[p] / COLS_PER_BLOCK;
  }
  const int totalBlocks = nb[0] + nb[1] + nb[2];
  const int rb = ((nb[0] + 15) / 16) + ((nb[1] + 15) / 16) + ((nb[2] + 15) / 16);

  const size_t partialBytes = (size_t)totalBlocks * 800 * sizeof(float);
  const size_t finalBytes   = (size_t)2400 * sizeof(double);
  const bool partialMode    = (ws_size >= partialBytes + finalBytes);

  char* wsb      = (char*)d_ws;
  float* partial = partialMode ? (float*)wsb : nullptr;
  double* finalG = (double*)(wsb + (partialMode ? partialBytes : 0));

  hipMemsetAsync(finalG, 0, finalBytes, stream);

  EpsList E;
  const double base = 0.95 * 0.95;
  for (int n = 0; n < NSTEP; ++n) {
    double v = pow(base, (double)n);
    if (v < 0.0025) v = 0.0025;
    E.e[n] = (float)v;
  }

  GramArgs A;
  A.x0 = xs[0]; A.y0 = ys[0];
  A.x1 = xs[1]; A.y1 = ys[1];
  A.x2 = xs[2]; A.y2 = ys[2];
  A.M0 = Ms[0]; A.M1 = Ms[1]; A.M2 = Ms[2];
  A.bs1 = nb[0]; A.bs2 = nb[0] + nb[1]; A.bsTot = totalBlocks;
  A.partial = partial; A.finalG = finalG;
  A.atomicMode = partialMode ? 0 : 1;

  gram_kernel<<<dim3(totalBlocks), dim3(TPB), 0, stream>>>(A);
  if (partialMode)
    reduce_kernel<<<dim3(rb), dim3(256), 0, stream>>>(partial, finalG, nb[0], nb[1], nb[2]);
  sinkhorn_kernel<<<dim3(1), dim3(384), 0, stream>>>(finalG, (float*)d_out, E);
}